// Round 1
// baseline (585.903 us; speedup 1.0000x reference)
//
#include <hip/hip_runtime.h>
#include <hip/hip_bf16.h>

#define NB 32
#define SS 1024
#define DD 768

typedef __attribute__((ext_vector_type(8))) short bf16x8;
typedef __attribute__((ext_vector_type(4))) float f32x4;

__device__ inline ushort f2bf(float f) {
    union { float f; unsigned u; } x;
    x.f = f;
    unsigned r = (x.u + 0x7fffu + ((x.u >> 16) & 1u)) >> 16;
    return (ushort)r;
}

#define GLOBAL_PTR(x) ((const __attribute__((address_space(1))) void*)(x))
#define LDS_PTR(x)    ((__attribute__((address_space(3))) void*)(x))

// ---------------------------------------------------------------- K0: weights transpose+convert: wT[n][k] = bf16([wq|wk][k][n])
__global__ void k_wt(const float* __restrict__ wq, const float* __restrict__ wk,
                     ushort* __restrict__ wT) {
    __shared__ float tile[32][33];
    int k0 = blockIdx.x * 32, n0 = blockIdx.y * 32;
    const float* src = (n0 < DD) ? wq : wk;
    int nn0 = (n0 < DD) ? n0 : n0 - DD;
#pragma unroll
    for (int i = 0; i < 4; i++) {
        int k = k0 + threadIdx.y + i * 8;
        tile[threadIdx.y + i * 8][threadIdx.x] = src[(size_t)k * DD + nn0 + threadIdx.x];
    }
    __syncthreads();
#pragma unroll
    for (int i = 0; i < 4; i++) {
        int n = n0 + threadIdx.y + i * 8;
        wT[(size_t)n * DD + k0 + threadIdx.x] = f2bf(tile[threadIdx.x][threadIdx.y + i * 8]);
    }
}

// ---------------------------------------------------------------- K0b: x = bf16(emb[tokens])  (32768 x 768)
__global__ void k_gather(const int* __restrict__ tokens, const float* __restrict__ emb,
                         ushort* __restrict__ xb) {
    int i = (blockIdx.x * 256 + threadIdx.x) * 4;   // 4 f32 per thread, never crosses row
    int row = i / DD;
    int col = i - row * DD;
    int tok = tokens[row];
    const float4 v = *(const float4*)(emb + (size_t)tok * DD + col);
    ushort4 o;
    o.x = f2bf(v.x); o.y = f2bf(v.y); o.z = f2bf(v.z); o.w = f2bf(v.w);
    *(ushort4*)(xb + (size_t)row * DD + col) = o;
}

// ---------------------------------------------------------------- GEMM (m97 structure): C = A(MxK) @ Bt(NxK)^T, bf16 in, K=768
// MODE 0: QK projection. grid (Mtiles=256, 12). n<768 -> q, else k. bf16 out.
// MODE 1: batched QK^T. grid (8, 8, 32). f32 out to s region.
template <int MODE>
__global__ __launch_bounds__(256, 2) void k_gemm(const ushort* __restrict__ A,
                                                 const ushort* __restrict__ Bt,
                                                 ushort* __restrict__ Cq,
                                                 ushort* __restrict__ Ck,
                                                 float* __restrict__ Cs) {
    constexpr int BK = 64;
    __shared__ ushort As[128 * BK];
    __shared__ ushort Bs[128 * BK];
    const int tid = threadIdx.x;
    const int wave = tid >> 6, lane = tid & 63;
    const int ld = DD;
    size_t abase = (size_t)blockIdx.x * 128 * ld;
    size_t bbase = (size_t)blockIdx.y * 128 * ld;
    if (MODE == 1) {
        size_t z = blockIdx.z;
        abase += z * (size_t)SS * DD;
        bbase += z * (size_t)SS * DD;
    }
    f32x4 acc[4][4] = {};
    const int r = tid >> 3;            // staging row 0..31
    const int cc = (tid & 7) * 8;      // staging col (bf16 units)
    const int wm = (wave >> 1) * 64, wn = (wave & 1) * 64;
    const int lr = lane & 15, lc = (lane >> 4) * 8;

    for (int k0 = 0; k0 < DD; k0 += BK) {
        __syncthreads();
#pragma unroll
        for (int i = 0; i < 4; i++) {
            __builtin_amdgcn_global_load_lds(GLOBAL_PTR(A + abase + (size_t)(r + i * 32) * ld + k0 + cc),
                                             LDS_PTR(As + (r + i * 32) * BK + cc), 16, 0, 0);
            __builtin_amdgcn_global_load_lds(GLOBAL_PTR(Bt + bbase + (size_t)(r + i * 32) * ld + k0 + cc),
                                             LDS_PTR(Bs + (r + i * 32) * BK + cc), 16, 0, 0);
        }
        __syncthreads();
#pragma unroll
        for (int kk = 0; kk < 2; kk++) {
            bf16x8 af[4], bfv[4];
#pragma unroll
            for (int m = 0; m < 4; m++)
                af[m] = *(const bf16x8*)(As + (wm + m * 16 + lr) * BK + kk * 32 + lc);
#pragma unroll
            for (int n = 0; n < 4; n++)
                bfv[n] = *(const bf16x8*)(Bs + (wn + n * 16 + lr) * BK + kk * 32 + lc);
#pragma unroll
            for (int m = 0; m < 4; m++)
#pragma unroll
                for (int n = 0; n < 4; n++)
                    acc[m][n] = __builtin_amdgcn_mfma_f32_16x16x32_bf16(af[m], bfv[n], acc[m][n], 0, 0, 0);
        }
    }

    const int rowbase = blockIdx.x * 128 + wm + (lane >> 4) * 4;
    if (MODE == 0) {
        const int tnv = blockIdx.y;
        ushort* Cp = (tnv < 6) ? Cq : Ck;
        const int colbase = tnv * 128 - (tnv < 6 ? 0 : DD) + wn + (lane & 15);
#pragma unroll
        for (int m = 0; m < 4; m++)
#pragma unroll
            for (int n = 0; n < 4; n++)
#pragma unroll
                for (int j = 0; j < 4; j++)
                    Cp[(size_t)(rowbase + m * 16 + j) * DD + colbase + n * 16] = f2bf(acc[m][n][j]);
    } else {
        float* Co = Cs + (size_t)blockIdx.z * SS * SS;
        const int colbase = blockIdx.y * 128 + wn + (lane & 15);
#pragma unroll
        for (int m = 0; m < 4; m++)
#pragma unroll
            for (int n = 0; n < 4; n++)
#pragma unroll
                for (int j = 0; j < 4; j++)
                    Co[(size_t)(rowbase + m * 16 + j) * SS + colbase + n * 16] = acc[m][n][j];
    }
}

// ---------------------------------------------------------------- K3: in-place masked softmax per row of a
__global__ __launch_bounds__(256) void k_softmax(float* __restrict__ a, const int* __restrict__ mask) {
    const int rid = blockIdx.x;
    const int b = rid >> 10, rr = rid & 1023;
    float* row = a + (size_t)b * SS * SS + (size_t)rr * SS;
    const int* mrow = mask + b * SS;
    const int t = threadIdx.x * 4;
    float4 v = *(float4*)(row + t);
    const int4 mk = *(const int4*)(mrow + t);
    float x0 = v.x + (mk.x ? -1e9f : 0.0f);
    float x1 = v.y + (mk.y ? -1e9f : 0.0f);
    float x2 = v.z + (mk.z ? -1e9f : 0.0f);
    float x3 = v.w + (mk.w ? -1e9f : 0.0f);
    float mx = fmaxf(fmaxf(x0, x1), fmaxf(x2, x3));
#pragma unroll
    for (int off = 32; off; off >>= 1) mx = fmaxf(mx, __shfl_xor(mx, off));
    __shared__ float redm[4], reds[4];
    if ((threadIdx.x & 63) == 0) redm[threadIdx.x >> 6] = mx;
    __syncthreads();
    mx = fmaxf(fmaxf(redm[0], redm[1]), fmaxf(redm[2], redm[3]));
    float e0 = expf(x0 - mx), e1 = expf(x1 - mx), e2 = expf(x2 - mx), e3 = expf(x3 - mx);
    float sm = e0 + e1 + e2 + e3;
#pragma unroll
    for (int off = 32; off; off >>= 1) sm += __shfl_xor(sm, off);
    if ((threadIdx.x & 63) == 0) reds[threadIdx.x >> 6] = sm;
    __syncthreads();
    sm = reds[0] + reds[1] + reds[2] + reds[3];
    const float inv = 1.0f / sm;
    v.x = e0 * inv; v.y = e1 * inv; v.z = e2 * inv; v.w = e3 * inv;
    *(float4*)(row + t) = v;
}

// ---------------------------------------------------------------- K4a: partial xbar[b][k] = sum_t a[b,0,t]*emb[tok[b,t]][k]
__global__ __launch_bounds__(256) void k_xbar(const float* __restrict__ a, const int* __restrict__ tokens,
                                              const float* __restrict__ emb, float* __restrict__ part) {
    const int b = blockIdx.x >> 3, c = blockIdx.x & 7;
    __shared__ float a0s[128];
    __shared__ int toks[128];
    const int tid = threadIdx.x;
    if (tid < 128) {
        a0s[tid] = a[(size_t)b * SS * SS + c * 128 + tid];
        toks[tid] = tokens[b * SS + c * 128 + tid];
    }
    __syncthreads();
    float acc0 = 0.f, acc1 = 0.f, acc2 = 0.f;
#pragma unroll 4
    for (int t = 0; t < 128; t++) {
        const float at = a0s[t];
        const float* er = emb + (size_t)toks[t] * DD;
        acc0 = fmaf(at, er[tid], acc0);
        acc1 = fmaf(at, er[tid + 256], acc1);
        acc2 = fmaf(at, er[tid + 512], acc2);
    }
    float* p = part + ((size_t)c * NB + b) * DD;
    p[tid] = acc0; p[tid + 256] = acc1; p[tid + 512] = acc2;
}

__device__ inline float block_sum(float v, float* red, int tid) {
#pragma unroll
    for (int off = 32; off; off >>= 1) v += __shfl_xor(v, off);
    __syncthreads();
    if ((tid & 63) == 0) red[tid >> 6] = v;
    __syncthreads();
    return red[0] + red[1] + red[2] + red[3];
}

// ---------------------------------------------------------------- K4b: per-batch head: cls = xbar@wv, LN, GELU-MLP, logits
__global__ __launch_bounds__(256) void k_head(const float* __restrict__ part, const float* __restrict__ wv,
                                              const float* __restrict__ ln_g, const float* __restrict__ ln_b,
                                              const float* __restrict__ w1, const float* __restrict__ b1,
                                              const float* __restrict__ wh, const float* __restrict__ bh,
                                              float* __restrict__ out) {
    const int b = blockIdx.x, tid = threadIdx.x;
    __shared__ float xb[DD];
    __shared__ float hs[DD];
    __shared__ float red[4];
#pragma unroll
    for (int j = 0; j < 3; j++) {
        const int k = tid + j * 256;
        float s = 0.f;
#pragma unroll
        for (int c = 0; c < 8; c++) s += part[((size_t)c * NB + b) * DD + k];
        xb[k] = s;
    }
    __syncthreads();
    float cls[3];
#pragma unroll
    for (int j = 0; j < 3; j++) {
        const int d = tid + j * 256;
        float s = 0.f;
#pragma unroll 8
        for (int k = 0; k < DD; k++) s = fmaf(xb[k], wv[(size_t)k * DD + d], s);
        cls[j] = s;
    }
    const float mu = block_sum(cls[0] + cls[1] + cls[2], red, tid) * (1.0f / DD);
    float dv = 0.f;
#pragma unroll
    for (int j = 0; j < 3; j++) { const float d = cls[j] - mu; dv += d * d; }
    const float var = block_sum(dv, red, tid) * (1.0f / DD);
    const float sc = 1.0f / sqrtf(var + 1e-5f);
#pragma unroll
    for (int j = 0; j < 3; j++) {
        const int d = tid + j * 256;
        hs[d] = (cls[j] - mu) * sc * ln_g[d] + ln_b[d];
    }
    __syncthreads();
    float l0 = 0.f, l1 = 0.f;
#pragma unroll
    for (int j = 0; j < 3; j++) {
        const int jj = tid + j * 256;
        float p = b1[jj];
#pragma unroll 8
        for (int d = 0; d < DD; d++) p = fmaf(hs[d], w1[(size_t)d * DD + jj], p);
        const float g = 0.5f * p * (1.0f + erff(p * 0.70710678118654752f));
        l0 = fmaf(g, wh[jj * 2 + 0], l0);
        l1 = fmaf(g, wh[jj * 2 + 1], l1);
    }
    l0 = block_sum(l0, red, tid);
    __syncthreads();
    l1 = block_sum(l1, red, tid);
    if (tid == 0) {
        out[b * 2 + 0] = l0 + bh[0];
        out[b * 2 + 1] = l1 + bh[1];
    }
}

// ----------------------------------------------------------------
extern "C" void kernel_launch(void* const* d_in, const int* in_sizes, int n_in,
                              void* d_out, int out_size, void* d_ws, size_t ws_size,
                              hipStream_t stream) {
    const int*   tokens = (const int*)d_in[0];
    const int*   mask   = (const int*)d_in[1];
    const float* emb    = (const float*)d_in[2];
    const float* wq     = (const float*)d_in[3];
    const float* wk     = (const float*)d_in[4];
    const float* wv     = (const float*)d_in[5];
    const float* ln_g   = (const float*)d_in[6];
    const float* ln_b   = (const float*)d_in[7];
    const float* w1     = (const float*)d_in[8];
    const float* b1     = (const float*)d_in[9];
    const float* wh     = (const float*)d_in[10];
    const float* bh     = (const float*)d_in[11];
    float* out = (float*)d_out;

    char* ws = (char*)d_ws;
    const size_t XB = (size_t)NB * SS * DD * 2;   // 50,331,648 B
    ushort* xb  = (ushort*)ws;
    ushort* qb  = (ushort*)(ws + XB);
    ushort* kb  = (ushort*)(ws + 2 * XB);
    ushort* wT  = (ushort*)(ws + 3 * XB);                 // 1536*768*2 = 2,359,296 B
    float*  part = (float*)(ws + 3 * XB + 2359296);       // 8*32*768*4 = 786,432 B

    float* s_region = out + 64;  // a region: B*S*S floats

    k_wt<<<dim3(24, 48), dim3(32, 8), 0, stream>>>(wq, wk, wT);
    k_gather<<<24576, 256, 0, stream>>>(tokens, emb, xb);
    k_gemm<0><<<dim3(256, 12), 256, 0, stream>>>(xb, wT, qb, kb, nullptr);
    k_gemm<1><<<dim3(8, 8, 32), 256, 0, stream>>>(qb, kb, nullptr, nullptr, s_region);
    k_softmax<<<32768, 256, 0, stream>>>(s_region, mask);
    k_xbar<<<256, 256, 0, stream>>>(s_region, tokens, emb, part);
    k_head<<<32, 256, 0, stream>>>(part, wv, ln_g, ln_b, w1, b1, wh, bh, out);
}

// Round 2
// 400.178 us; speedup vs baseline: 1.4641x; 1.4641x over previous
//
#include <hip/hip_runtime.h>
#include <hip/hip_bf16.h>

#define NB 32
#define SS 1024
#define DD 768

typedef __attribute__((ext_vector_type(8))) short bf16x8;
typedef __attribute__((ext_vector_type(4))) float f32x4;

__device__ inline ushort f2bf(float f) {
    union { float f; unsigned u; } x;
    x.f = f;
    unsigned r = (x.u + 0x7fffu + ((x.u >> 16) & 1u)) >> 16;
    return (ushort)r;
}

#define GLOBAL_PTR(x) ((const __attribute__((address_space(1))) void*)(x))
#define LDS_PTR(x)    ((__attribute__((address_space(3))) void*)(x))

// ---------------------------------------------------------------- K0: weights transpose+convert: wT[n][k] = bf16([wq|wk][k][n])
__global__ void k_wt(const float* __restrict__ wq, const float* __restrict__ wk,
                     ushort* __restrict__ wT) {
    __shared__ float tile[32][33];
    int k0 = blockIdx.x * 32, n0 = blockIdx.y * 32;
    const float* src = (n0 < DD) ? wq : wk;
    int nn0 = (n0 < DD) ? n0 : n0 - DD;
#pragma unroll
    for (int i = 0; i < 4; i++) {
        int k = k0 + threadIdx.y + i * 8;
        tile[threadIdx.y + i * 8][threadIdx.x] = src[(size_t)k * DD + nn0 + threadIdx.x];
    }
    __syncthreads();
#pragma unroll
    for (int i = 0; i < 4; i++) {
        int n = n0 + threadIdx.y + i * 8;
        wT[(size_t)n * DD + k0 + threadIdx.x] = f2bf(tile[threadIdx.x][threadIdx.y + i * 8]);
    }
}

// ---------------------------------------------------------------- K0b: x = bf16(emb[tokens])  (32768 x 768)
__global__ void k_gather(const int* __restrict__ tokens, const float* __restrict__ emb,
                         ushort* __restrict__ xb) {
    int i = (blockIdx.x * 256 + threadIdx.x) * 4;   // 4 f32 per thread, never crosses row
    int row = i / DD;
    int col = i - row * DD;
    int tok = tokens[row];
    const float4 v = *(const float4*)(emb + (size_t)tok * DD + col);
    ushort4 o;
    o.x = f2bf(v.x); o.y = f2bf(v.y); o.z = f2bf(v.z); o.w = f2bf(v.w);
    *(ushort4*)(xb + (size_t)row * DD + col) = o;
}

// ---------------------------------------------------------------- GEMM (m97 structure): C = A(MxK) @ Bt(NxK)^T, bf16 in, K=768
// MODE 0: QK projection. grid (Mtiles=256, 12). n<768 -> q, else k. bf16 out.
// MODE 1: batched QK^T. grid (8, 8, 32). f32 out to s region.
template <int MODE>
__global__ __launch_bounds__(256, 2) void k_gemm(const ushort* __restrict__ A,
                                                 const ushort* __restrict__ Bt,
                                                 ushort* __restrict__ Cq,
                                                 ushort* __restrict__ Ck,
                                                 float* __restrict__ Cs) {
    constexpr int BK = 64;
    __shared__ ushort As[128 * BK];
    __shared__ ushort Bs[128 * BK];
    const int tid = threadIdx.x;
    const int wave = tid >> 6, lane = tid & 63;
    const int ld = DD;
    size_t abase = (size_t)blockIdx.x * 128 * ld;
    size_t bbase = (size_t)blockIdx.y * 128 * ld;
    if (MODE == 1) {
        size_t z = blockIdx.z;
        abase += z * (size_t)SS * DD;
        bbase += z * (size_t)SS * DD;
    }
    f32x4 acc[4][4] = {};
    const int r = tid >> 3;            // staging row 0..31
    const int cc = (tid & 7) * 8;      // staging col (bf16 units)
    const int wm = (wave >> 1) * 64, wn = (wave & 1) * 64;
    const int lr = lane & 15, lc = (lane >> 4) * 8;

    for (int k0 = 0; k0 < DD; k0 += BK) {
        __syncthreads();
#pragma unroll
        for (int i = 0; i < 4; i++) {
            __builtin_amdgcn_global_load_lds(GLOBAL_PTR(A + abase + (size_t)(r + i * 32) * ld + k0 + cc),
                                             LDS_PTR(As + (r + i * 32) * BK + cc), 16, 0, 0);
            __builtin_amdgcn_global_load_lds(GLOBAL_PTR(Bt + bbase + (size_t)(r + i * 32) * ld + k0 + cc),
                                             LDS_PTR(Bs + (r + i * 32) * BK + cc), 16, 0, 0);
        }
        __syncthreads();
#pragma unroll
        for (int kk = 0; kk < 2; kk++) {
            bf16x8 af[4], bfv[4];
#pragma unroll
            for (int m = 0; m < 4; m++)
                af[m] = *(const bf16x8*)(As + (wm + m * 16 + lr) * BK + kk * 32 + lc);
#pragma unroll
            for (int n = 0; n < 4; n++)
                bfv[n] = *(const bf16x8*)(Bs + (wn + n * 16 + lr) * BK + kk * 32 + lc);
#pragma unroll
            for (int m = 0; m < 4; m++)
#pragma unroll
                for (int n = 0; n < 4; n++)
                    acc[m][n] = __builtin_amdgcn_mfma_f32_16x16x32_bf16(af[m], bfv[n], acc[m][n], 0, 0, 0);
        }
    }

    const int rowbase = blockIdx.x * 128 + wm + (lane >> 4) * 4;
    if (MODE == 0) {
        const int tnv = blockIdx.y;
        ushort* Cp = (tnv < 6) ? Cq : Ck;
        const int colbase = tnv * 128 - (tnv < 6 ? 0 : DD) + wn + (lane & 15);
#pragma unroll
        for (int m = 0; m < 4; m++)
#pragma unroll
            for (int n = 0; n < 4; n++)
#pragma unroll
                for (int j = 0; j < 4; j++)
                    Cp[(size_t)(rowbase + m * 16 + j) * DD + colbase + n * 16] = f2bf(acc[m][n][j]);
    } else {
        float* Co = Cs + (size_t)blockIdx.z * SS * SS;
        const int colbase = blockIdx.y * 128 + wn + (lane & 15);
#pragma unroll
        for (int m = 0; m < 4; m++)
#pragma unroll
            for (int n = 0; n < 4; n++)
#pragma unroll
                for (int j = 0; j < 4; j++)
                    Co[(size_t)(rowbase + m * 16 + j) * SS + colbase + n * 16] = acc[m][n][j];
    }
}

// ---------------------------------------------------------------- K3: in-place masked softmax per row of a
__global__ __launch_bounds__(256) void k_softmax(float* __restrict__ a, const int* __restrict__ mask) {
    const int rid = blockIdx.x;
    const int b = rid >> 10, rr = rid & 1023;
    float* row = a + (size_t)b * SS * SS + (size_t)rr * SS;
    const int* mrow = mask + b * SS;
    const int t = threadIdx.x * 4;
    float4 v = *(float4*)(row + t);
    const int4 mk = *(const int4*)(mrow + t);
    float x0 = v.x + (mk.x ? -1e9f : 0.0f);
    float x1 = v.y + (mk.y ? -1e9f : 0.0f);
    float x2 = v.z + (mk.z ? -1e9f : 0.0f);
    float x3 = v.w + (mk.w ? -1e9f : 0.0f);
    float mx = fmaxf(fmaxf(x0, x1), fmaxf(x2, x3));
#pragma unroll
    for (int off = 32; off; off >>= 1) mx = fmaxf(mx, __shfl_xor(mx, off));
    __shared__ float redm[4], reds[4];
    if ((threadIdx.x & 63) == 0) redm[threadIdx.x >> 6] = mx;
    __syncthreads();
    mx = fmaxf(fmaxf(redm[0], redm[1]), fmaxf(redm[2], redm[3]));
    float e0 = expf(x0 - mx), e1 = expf(x1 - mx), e2 = expf(x2 - mx), e3 = expf(x3 - mx);
    float sm = e0 + e1 + e2 + e3;
#pragma unroll
    for (int off = 32; off; off >>= 1) sm += __shfl_xor(sm, off);
    if ((threadIdx.x & 63) == 0) reds[threadIdx.x >> 6] = sm;
    __syncthreads();
    sm = reds[0] + reds[1] + reds[2] + reds[3];
    const float inv = 1.0f / sm;
    v.x = e0 * inv; v.y = e1 * inv; v.z = e2 * inv; v.w = e3 * inv;
    *(float4*)(row + t) = v;
}

// ---------------------------------------------------------------- K4a: partial xbar[b][k] = sum_t a[b,0,t]*emb[tok[b,t]][k]
__global__ __launch_bounds__(256) void k_xbar(const float* __restrict__ a, const int* __restrict__ tokens,
                                              const float* __restrict__ emb, float* __restrict__ part) {
    const int b = blockIdx.x >> 3, c = blockIdx.x & 7;
    __shared__ float a0s[128];
    __shared__ int toks[128];
    const int tid = threadIdx.x;
    if (tid < 128) {
        a0s[tid] = a[(size_t)b * SS * SS + c * 128 + tid];
        toks[tid] = tokens[b * SS + c * 128 + tid];
    }
    __syncthreads();
    float acc0 = 0.f, acc1 = 0.f, acc2 = 0.f;
#pragma unroll 4
    for (int t = 0; t < 128; t++) {
        const float at = a0s[t];
        const float* er = emb + (size_t)toks[t] * DD;
        acc0 = fmaf(at, er[tid], acc0);
        acc1 = fmaf(at, er[tid + 256], acc1);
        acc2 = fmaf(at, er[tid + 512], acc2);
    }
    float* p = part + ((size_t)c * NB + b) * DD;
    p[tid] = acc0; p[tid + 256] = acc1; p[tid + 512] = acc2;
}

// ---------------------------------------------------------------- K5: cls[b][c] = sum_k xbar[b][k] * wv[k][c]
// grid (6 ctiles, 32 b), 128 threads. xbar folded from 8 partials into LDS.
__global__ __launch_bounds__(128) void k_cls(const float* __restrict__ part, const float* __restrict__ wv,
                                             float* __restrict__ cls) {
    const int b = blockIdx.y, tid = threadIdx.x;
    const int c = blockIdx.x * 128 + tid;
    __shared__ float xb[DD];
#pragma unroll
    for (int j = 0; j < 6; j++) {
        const int k = tid + j * 128;
        float s = 0.f;
#pragma unroll
        for (int p = 0; p < 8; p++) s += part[((size_t)p * NB + b) * DD + k];
        xb[k] = s;
    }
    __syncthreads();
    float acc = 0.f;
#pragma unroll 8
    for (int k = 0; k < DD; k++) acc = fmaf(xb[k], wv[(size_t)k * DD + c], acc);
    cls[(size_t)b * DD + c] = acc;
}

__device__ inline float block_sum256(float v, float* red, int tid) {
#pragma unroll
    for (int off = 32; off; off >>= 1) v += __shfl_xor(v, off);
    __syncthreads();
    if ((tid & 63) == 0) red[tid >> 6] = v;
    __syncthreads();
    return red[0] + red[1] + red[2] + red[3];
}

// ---------------------------------------------------------------- K6: LayerNorm per batch: hs = (cls-mu)*rsqrt(var+eps)*g + b
__global__ __launch_bounds__(256) void k_ln(const float* __restrict__ cls, const float* __restrict__ ln_g,
                                            const float* __restrict__ ln_b, float* __restrict__ hs) {
    const int b = blockIdx.x, tid = threadIdx.x;
    __shared__ float red[4];
    float v[3];
#pragma unroll
    for (int j = 0; j < 3; j++) v[j] = cls[(size_t)b * DD + tid + j * 256];
    const float mu = block_sum256(v[0] + v[1] + v[2], red, tid) * (1.0f / DD);
    float dv = 0.f;
#pragma unroll
    for (int j = 0; j < 3; j++) { const float d = v[j] - mu; dv += d * d; }
    __syncthreads();
    const float var = block_sum256(dv, red, tid) * (1.0f / DD);
    const float sc = 1.0f / sqrtf(var + 1e-5f);
#pragma unroll
    for (int j = 0; j < 3; j++) {
        const int d = tid + j * 256;
        hs[(size_t)b * DD + d] = (v[j] - mu) * sc * ln_g[d] + ln_b[d];
    }
}

// ---------------------------------------------------------------- K7: g = gelu(hs@w1+b1); partial logits per 128-col chunk
// grid (6 ctiles, 32 b), 128 threads.
__global__ __launch_bounds__(128) void k_mlp(const float* __restrict__ hs, const float* __restrict__ w1,
                                             const float* __restrict__ b1, const float* __restrict__ wh,
                                             float* __restrict__ part_l) {
    const int b = blockIdx.y, tid = threadIdx.x;
    const int j = blockIdx.x * 128 + tid;
    __shared__ float h[DD];
#pragma unroll
    for (int q = 0; q < 6; q++) h[tid + q * 128] = hs[(size_t)b * DD + tid + q * 128];
    __syncthreads();
    float p = b1[j];
#pragma unroll 8
    for (int d = 0; d < DD; d++) p = fmaf(h[d], w1[(size_t)d * DD + j], p);
    const float g = 0.5f * p * (1.0f + erff(p * 0.70710678118654752f));
    float l0 = g * wh[j * 2 + 0];
    float l1 = g * wh[j * 2 + 1];
#pragma unroll
    for (int off = 32; off; off >>= 1) { l0 += __shfl_xor(l0, off); l1 += __shfl_xor(l1, off); }
    __shared__ float r0[2], r1[2];
    if ((tid & 63) == 0) { r0[tid >> 6] = l0; r1[tid >> 6] = l1; }
    __syncthreads();
    if (tid == 0) {
        part_l[((size_t)b * 6 + blockIdx.x) * 2 + 0] = r0[0] + r0[1];
        part_l[((size_t)b * 6 + blockIdx.x) * 2 + 1] = r1[0] + r1[1];
    }
}

// ---------------------------------------------------------------- K8: final logits reduce
__global__ __launch_bounds__(64) void k_final(const float* __restrict__ part_l, const float* __restrict__ bh,
                                              float* __restrict__ out) {
    const int b = threadIdx.x;
    if (b < NB) {
        float l0 = bh[0], l1 = bh[1];
#pragma unroll
        for (int c = 0; c < 6; c++) {
            l0 += part_l[((size_t)b * 6 + c) * 2 + 0];
            l1 += part_l[((size_t)b * 6 + c) * 2 + 1];
        }
        out[b * 2 + 0] = l0;
        out[b * 2 + 1] = l1;
    }
}

// ----------------------------------------------------------------
extern "C" void kernel_launch(void* const* d_in, const int* in_sizes, int n_in,
                              void* d_out, int out_size, void* d_ws, size_t ws_size,
                              hipStream_t stream) {
    const int*   tokens = (const int*)d_in[0];
    const int*   mask   = (const int*)d_in[1];
    const float* emb    = (const float*)d_in[2];
    const float* wq     = (const float*)d_in[3];
    const float* wk     = (const float*)d_in[4];
    const float* wv     = (const float*)d_in[5];
    const float* ln_g   = (const float*)d_in[6];
    const float* ln_b   = (const float*)d_in[7];
    const float* w1     = (const float*)d_in[8];
    const float* b1     = (const float*)d_in[9];
    const float* wh     = (const float*)d_in[10];
    const float* bh     = (const float*)d_in[11];
    float* out = (float*)d_out;

    char* ws = (char*)d_ws;
    const size_t XB = (size_t)NB * SS * DD * 2;   // 50,331,648 B
    ushort* xb  = (ushort*)ws;
    ushort* qb  = (ushort*)(ws + XB);
    ushort* kb  = (ushort*)(ws + 2 * XB);
    ushort* wT  = (ushort*)(ws + 3 * XB);                 // 1536*768*2 = 2,359,296 B
    char*   p4  = ws + 3 * XB + 2359296;
    float*  part   = (float*)p4;                          // 8*32*768*4 = 786,432 B
    float*  cls    = (float*)(p4 + 786432);               // 32*768*4 = 98,304 B
    float*  hsb    = (float*)(p4 + 786432 + 98304);       // 32*768*4 = 98,304 B
    float*  part_l = (float*)(p4 + 786432 + 2 * 98304);   // 32*6*2*4 = 1,536 B

    float* s_region = out + 64;  // a region: B*S*S floats

    k_wt<<<dim3(24, 48), dim3(32, 8), 0, stream>>>(wq, wk, wT);
    k_gather<<<24576, 256, 0, stream>>>(tokens, emb, xb);
    k_gemm<0><<<dim3(256, 12), 256, 0, stream>>>(xb, wT, qb, kb, nullptr);
    k_gemm<1><<<dim3(8, 8, 32), 256, 0, stream>>>(qb, kb, nullptr, nullptr, s_region);
    k_softmax<<<32768, 256, 0, stream>>>(s_region, mask);
    k_xbar<<<256, 256, 0, stream>>>(s_region, tokens, emb, part);
    k_cls<<<dim3(6, NB), 128, 0, stream>>>(part, wv, cls);
    k_ln<<<NB, 256, 0, stream>>>(cls, ln_g, ln_b, hsb);
    k_mlp<<<dim3(6, NB), 128, 0, stream>>>(hsb, w1, b1, wh, part_l);
    k_final<<<1, 64, 0, stream>>>(part_l, bh, out);
}

// Round 3
// 369.274 us; speedup vs baseline: 1.5866x; 1.0837x over previous
//
#include <hip/hip_runtime.h>
#include <hip/hip_bf16.h>

#define NB 32
#define SS 1024
#define DD 768

typedef __attribute__((ext_vector_type(8))) short bf16x8;
typedef __attribute__((ext_vector_type(4))) float f32x4;

__device__ inline ushort f2bf(float f) {
    union { float f; unsigned u; } x;
    x.f = f;
    unsigned r = (x.u + 0x7fffu + ((x.u >> 16) & 1u)) >> 16;
    return (ushort)r;
}

#define GLOBAL_PTR(x) ((const __attribute__((address_space(1))) void*)(x))
#define LDS_PTR(x)    ((__attribute__((address_space(3))) void*)(x))

// ---------------------------------------------------------------- K0: f32 -> bf16 flat convert of wq and wk (natural layout)
__global__ void k_cvt(const float* __restrict__ wq, const float* __restrict__ wk,
                      ushort* __restrict__ wqb, ushort* __restrict__ wkb) {
    const int i = (blockIdx.x * 256 + threadIdx.x) * 4;
    const float* src = blockIdx.y ? wk : wq;
    ushort* dst = blockIdx.y ? wkb : wqb;
    const float4 v = *(const float4*)(src + i);
    ushort4 o;
    o.x = f2bf(v.x); o.y = f2bf(v.y); o.z = f2bf(v.z); o.w = f2bf(v.w);
    *(ushort4*)(dst + i) = o;
}

// ---------------------------------------------------------------- K0b: x = bf16(emb[tokens])  (32768 x 768)
__global__ void k_gather(const int* __restrict__ tokens, const float* __restrict__ emb,
                         ushort* __restrict__ xb) {
    int i = (blockIdx.x * 256 + threadIdx.x) * 4;   // 4 f32 per thread, never crosses row
    int row = i / DD;
    int col = i - row * DD;
    int tok = tokens[row];
    const float4 v = *(const float4*)(emb + (size_t)tok * DD + col);
    ushort4 o;
    o.x = f2bf(v.x); o.y = f2bf(v.y); o.z = f2bf(v.z); o.w = f2bf(v.w);
    *(ushort4*)(xb + (size_t)row * DD + col) = o;
}

// ---------------------------------------------------------------- GEMM (m97 structure): C = A(MxK) @ Bt(NxK)^T, bf16 in, K=768
// MODE 0: bf16 out to Cb (ldc=DD). Used for Wt = wk@wq^T (grid 6x6) and y = x@Wt^T (grid 256x6).
// MODE 1: batched f32 out to Cs (ldc=SS). s = y @ x^T. grid (8, 8, 32).
template <int MODE>
__global__ __launch_bounds__(256, 2) void k_gemm(const ushort* __restrict__ A,
                                                 const ushort* __restrict__ Bt,
                                                 ushort* __restrict__ Cb,
                                                 float* __restrict__ Cs) {
    constexpr int BK = 64;
    __shared__ ushort As[128 * BK];
    __shared__ ushort Bs[128 * BK];
    const int tid = threadIdx.x;
    const int wave = tid >> 6, lane = tid & 63;
    const int ld = DD;
    size_t abase = (size_t)blockIdx.x * 128 * ld;
    size_t bbase = (size_t)blockIdx.y * 128 * ld;
    if (MODE == 1) {
        size_t z = blockIdx.z;
        abase += z * (size_t)SS * DD;
        bbase += z * (size_t)SS * DD;
    }
    f32x4 acc[4][4] = {};
    const int r = tid >> 3;            // staging row 0..31
    const int cc = (tid & 7) * 8;      // staging col (bf16 units)
    const int wm = (wave >> 1) * 64, wn = (wave & 1) * 64;
    const int lr = lane & 15, lc = (lane >> 4) * 8;

    for (int k0 = 0; k0 < DD; k0 += BK) {
        __syncthreads();
#pragma unroll
        for (int i = 0; i < 4; i++) {
            __builtin_amdgcn_global_load_lds(GLOBAL_PTR(A + abase + (size_t)(r + i * 32) * ld + k0 + cc),
                                             LDS_PTR(As + (r + i * 32) * BK + cc), 16, 0, 0);
            __builtin_amdgcn_global_load_lds(GLOBAL_PTR(Bt + bbase + (size_t)(r + i * 32) * ld + k0 + cc),
                                             LDS_PTR(Bs + (r + i * 32) * BK + cc), 16, 0, 0);
        }
        __syncthreads();
#pragma unroll
        for (int kk = 0; kk < 2; kk++) {
            bf16x8 af[4], bfv[4];
#pragma unroll
            for (int m = 0; m < 4; m++)
                af[m] = *(const bf16x8*)(As + (wm + m * 16 + lr) * BK + kk * 32 + lc);
#pragma unroll
            for (int n = 0; n < 4; n++)
                bfv[n] = *(const bf16x8*)(Bs + (wn + n * 16 + lr) * BK + kk * 32 + lc);
#pragma unroll
            for (int m = 0; m < 4; m++)
#pragma unroll
                for (int n = 0; n < 4; n++)
                    acc[m][n] = __builtin_amdgcn_mfma_f32_16x16x32_bf16(af[m], bfv[n], acc[m][n], 0, 0, 0);
        }
    }

    const int rowbase = blockIdx.x * 128 + wm + (lane >> 4) * 4;
    if (MODE == 0) {
        const int colbase = blockIdx.y * 128 + wn + (lane & 15);
#pragma unroll
        for (int m = 0; m < 4; m++)
#pragma unroll
            for (int n = 0; n < 4; n++)
#pragma unroll
                for (int j = 0; j < 4; j++)
                    Cb[(size_t)(rowbase + m * 16 + j) * DD + colbase + n * 16] = f2bf(acc[m][n][j]);
    } else {
        float* Co = Cs + (size_t)blockIdx.z * SS * SS;
        const int colbase = blockIdx.y * 128 + wn + (lane & 15);
#pragma unroll
        for (int m = 0; m < 4; m++)
#pragma unroll
            for (int n = 0; n < 4; n++)
#pragma unroll
                for (int j = 0; j < 4; j++)
                    Co[(size_t)(rowbase + m * 16 + j) * SS + colbase + n * 16] = acc[m][n][j];
    }
}

// ---------------------------------------------------------------- K3: in-place masked softmax per row of a
__global__ __launch_bounds__(256) void k_softmax(float* __restrict__ a, const int* __restrict__ mask) {
    const int rid = blockIdx.x;
    const int b = rid >> 10, rr = rid & 1023;
    float* row = a + (size_t)b * SS * SS + (size_t)rr * SS;
    const int* mrow = mask + b * SS;
    const int t = threadIdx.x * 4;
    float4 v = *(float4*)(row + t);
    const int4 mk = *(const int4*)(mrow + t);
    float x0 = v.x + (mk.x ? -1e9f : 0.0f);
    float x1 = v.y + (mk.y ? -1e9f : 0.0f);
    float x2 = v.z + (mk.z ? -1e9f : 0.0f);
    float x3 = v.w + (mk.w ? -1e9f : 0.0f);
    float mx = fmaxf(fmaxf(x0, x1), fmaxf(x2, x3));
#pragma unroll
    for (int off = 32; off; off >>= 1) mx = fmaxf(mx, __shfl_xor(mx, off));
    __shared__ float redm[4], reds[4];
    if ((threadIdx.x & 63) == 0) redm[threadIdx.x >> 6] = mx;
    __syncthreads();
    mx = fmaxf(fmaxf(redm[0], redm[1]), fmaxf(redm[2], redm[3]));
    float e0 = expf(x0 - mx), e1 = expf(x1 - mx), e2 = expf(x2 - mx), e3 = expf(x3 - mx);
    float sm = e0 + e1 + e2 + e3;
#pragma unroll
    for (int off = 32; off; off >>= 1) sm += __shfl_xor(sm, off);
    if ((threadIdx.x & 63) == 0) reds[threadIdx.x >> 6] = sm;
    __syncthreads();
    sm = reds[0] + reds[1] + reds[2] + reds[3];
    const float inv = 1.0f / sm;
    v.x = e0 * inv; v.y = e1 * inv; v.z = e2 * inv; v.w = e3 * inv;
    *(float4*)(row + t) = v;
}

// ---------------------------------------------------------------- K4a: partial xbar[b][k] = sum_t a[b,0,t]*emb[tok[b,t]][k]
__global__ __launch_bounds__(256) void k_xbar(const float* __restrict__ a, const int* __restrict__ tokens,
                                              const float* __restrict__ emb, float* __restrict__ part) {
    const int b = blockIdx.x >> 3, c = blockIdx.x & 7;
    __shared__ float a0s[128];
    __shared__ int toks[128];
    const int tid = threadIdx.x;
    if (tid < 128) {
        a0s[tid] = a[(size_t)b * SS * SS + c * 128 + tid];
        toks[tid] = tokens[b * SS + c * 128 + tid];
    }
    __syncthreads();
    float acc0 = 0.f, acc1 = 0.f, acc2 = 0.f;
#pragma unroll 4
    for (int t = 0; t < 128; t++) {
        const float at = a0s[t];
        const float* er = emb + (size_t)toks[t] * DD;
        acc0 = fmaf(at, er[tid], acc0);
        acc1 = fmaf(at, er[tid + 256], acc1);
        acc2 = fmaf(at, er[tid + 512], acc2);
    }
    float* p = part + ((size_t)c * NB + b) * DD;
    p[tid] = acc0; p[tid + 256] = acc1; p[tid + 512] = acc2;
}

// ---------------------------------------------------------------- K5: cls[b][c] = sum_k xbar[b][k] * wv[k][c]
// grid (6 ctiles, 32 b), 128 threads. xbar folded from 8 partials into LDS.
__global__ __launch_bounds__(128) void k_cls(const float* __restrict__ part, const float* __restrict__ wv,
                                             float* __restrict__ cls) {
    const int b = blockIdx.y, tid = threadIdx.x;
    const int c = blockIdx.x * 128 + tid;
    __shared__ float xb[DD];
#pragma unroll
    for (int j = 0; j < 6; j++) {
        const int k = tid + j * 128;
        float s = 0.f;
#pragma unroll
        for (int p = 0; p < 8; p++) s += part[((size_t)p * NB + b) * DD + k];
        xb[k] = s;
    }
    __syncthreads();
    float acc = 0.f;
#pragma unroll 8
    for (int k = 0; k < DD; k++) acc = fmaf(xb[k], wv[(size_t)k * DD + c], acc);
    cls[(size_t)b * DD + c] = acc;
}

__device__ inline float block_sum256(float v, float* red, int tid) {
#pragma unroll
    for (int off = 32; off; off >>= 1) v += __shfl_xor(v, off);
    __syncthreads();
    if ((tid & 63) == 0) red[tid >> 6] = v;
    __syncthreads();
    return red[0] + red[1] + red[2] + red[3];
}

// ---------------------------------------------------------------- K6: LayerNorm per batch: hs = (cls-mu)*rsqrt(var+eps)*g + b
__global__ __launch_bounds__(256) void k_ln(const float* __restrict__ cls, const float* __restrict__ ln_g,
                                            const float* __restrict__ ln_b, float* __restrict__ hs) {
    const int b = blockIdx.x, tid = threadIdx.x;
    __shared__ float red[4];
    float v[3];
#pragma unroll
    for (int j = 0; j < 3; j++) v[j] = cls[(size_t)b * DD + tid + j * 256];
    const float mu = block_sum256(v[0] + v[1] + v[2], red, tid) * (1.0f / DD);
    float dv = 0.f;
#pragma unroll
    for (int j = 0; j < 3; j++) { const float d = v[j] - mu; dv += d * d; }
    __syncthreads();
    const float var = block_sum256(dv, red, tid) * (1.0f / DD);
    const float sc = 1.0f / sqrtf(var + 1e-5f);
#pragma unroll
    for (int j = 0; j < 3; j++) {
        const int d = tid + j * 256;
        hs[(size_t)b * DD + d] = (v[j] - mu) * sc * ln_g[d] + ln_b[d];
    }
}

// ---------------------------------------------------------------- K7: g = gelu(hs@w1+b1); partial logits per 128-col chunk
// grid (6 ctiles, 32 b), 128 threads.
__global__ __launch_bounds__(128) void k_mlp(const float* __restrict__ hs, const float* __restrict__ w1,
                                             const float* __restrict__ b1, const float* __restrict__ wh,
                                             float* __restrict__ part_l) {
    const int b = blockIdx.y, tid = threadIdx.x;
    const int j = blockIdx.x * 128 + tid;
    __shared__ float h[DD];
#pragma unroll
    for (int q = 0; q < 6; q++) h[tid + q * 128] = hs[(size_t)b * DD + tid + q * 128];
    __syncthreads();
    float p = b1[j];
#pragma unroll 8
    for (int d = 0; d < DD; d++) p = fmaf(h[d], w1[(size_t)d * DD + j], p);
    const float g = 0.5f * p * (1.0f + erff(p * 0.70710678118654752f));
    float l0 = g * wh[j * 2 + 0];
    float l1 = g * wh[j * 2 + 1];
#pragma unroll
    for (int off = 32; off; off >>= 1) { l0 += __shfl_xor(l0, off); l1 += __shfl_xor(l1, off); }
    __shared__ float r0[2], r1[2];
    if ((tid & 63) == 0) { r0[tid >> 6] = l0; r1[tid >> 6] = l1; }
    __syncthreads();
    if (tid == 0) {
        part_l[((size_t)b * 6 + blockIdx.x) * 2 + 0] = r0[0] + r0[1];
        part_l[((size_t)b * 6 + blockIdx.x) * 2 + 1] = r1[0] + r1[1];
    }
}

// ---------------------------------------------------------------- K8: final logits reduce
__global__ __launch_bounds__(64) void k_final(const float* __restrict__ part_l, const float* __restrict__ bh,
                                              float* __restrict__ out) {
    const int b = threadIdx.x;
    if (b < NB) {
        float l0 = bh[0], l1 = bh[1];
#pragma unroll
        for (int c = 0; c < 6; c++) {
            l0 += part_l[((size_t)b * 6 + c) * 2 + 0];
            l1 += part_l[((size_t)b * 6 + c) * 2 + 1];
        }
        out[b * 2 + 0] = l0;
        out[b * 2 + 1] = l1;
    }
}

// ----------------------------------------------------------------
extern "C" void kernel_launch(void* const* d_in, const int* in_sizes, int n_in,
                              void* d_out, int out_size, void* d_ws, size_t ws_size,
                              hipStream_t stream) {
    const int*   tokens = (const int*)d_in[0];
    const int*   mask   = (const int*)d_in[1];
    const float* emb    = (const float*)d_in[2];
    const float* wq     = (const float*)d_in[3];
    const float* wk     = (const float*)d_in[4];
    const float* wv     = (const float*)d_in[5];
    const float* ln_g   = (const float*)d_in[6];
    const float* ln_b   = (const float*)d_in[7];
    const float* w1     = (const float*)d_in[8];
    const float* b1     = (const float*)d_in[9];
    const float* wh     = (const float*)d_in[10];
    const float* bh     = (const float*)d_in[11];
    float* out = (float*)d_out;

    char* ws = (char*)d_ws;
    const size_t XB = (size_t)NB * SS * DD * 2;   // 50,331,648 B
    const size_t WB = (size_t)DD * DD * 2;        // 1,179,648 B
    ushort* xb  = (ushort*)ws;                    // x bf16
    ushort* yb  = (ushort*)(ws + XB);             // y = x @ W bf16
    ushort* wqb = (ushort*)(ws + 2 * XB);         // wq bf16
    ushort* wkb = (ushort*)(ws + 2 * XB + WB);    // wk bf16
    ushort* Wt  = (ushort*)(ws + 2 * XB + 2 * WB);// Wt[e][d] = (wq wk^T)[d][e] bf16
    char*   p4  = ws + 2 * XB + 3 * WB;
    float*  part   = (float*)p4;                          // 8*32*768*4 = 786,432 B
    float*  cls    = (float*)(p4 + 786432);               // 32*768*4
    float*  hsb    = (float*)(p4 + 786432 + 98304);       // 32*768*4
    float*  part_l = (float*)(p4 + 786432 + 2 * 98304);   // 32*6*2*4

    float* s_region = out + 64;  // a region: B*S*S floats

    k_cvt<<<dim3(576, 2), 256, 0, stream>>>(wq, wk, wqb, wkb);
    k_gather<<<24576, 256, 0, stream>>>(tokens, emb, xb);
    // Wt = wk @ wq^T  (Wt[e][d] = sum_j wk[e,j] wq[d,j] = W[d,e])
    k_gemm<0><<<dim3(6, 6), 256, 0, stream>>>(wkb, wqb, Wt, nullptr);
    // y = x @ W  (y[s,e] = sum_d x[s,d] Wt[e,d])
    k_gemm<0><<<dim3(256, 6), 256, 0, stream>>>(xb, Wt, yb, nullptr);
    // s = y @ x^T (batched)
    k_gemm<1><<<dim3(8, 8, 32), 256, 0, stream>>>(yb, xb, nullptr, s_region);
    k_softmax<<<32768, 256, 0, stream>>>(s_region, mask);
    k_xbar<<<256, 256, 0, stream>>>(s_region, tokens, emb, part);
    k_cls<<<dim3(6, NB), 128, 0, stream>>>(part, wv, cls);
    k_ln<<<NB, 256, 0, stream>>>(cls, ln_g, ln_b, hsb);
    k_mlp<<<dim3(6, NB), 128, 0, stream>>>(hsb, w1, b1, wh, part_l);
    k_final<<<1, 64, 0, stream>>>(part_l, bh, out);
}